// Round 3
// baseline (544.380 us; speedup 1.0000x reference)
//
#include <hip/hip_runtime.h>
#include <math.h>

#define NPROP 2000
#define RPN_ROW (NPROP * 5)       // 10000 floats per row
#define SC_ROW  (NPROP * 2)       // 4000 floats per row
#define PANELTY_K 0.055f
#define HANN_W 0.42f
#define PI_F 3.14159265358979323846f

typedef float f4 __attribute__((ext_vector_type(4)));

// One block per row; 256 threads; each thread computes 4 consecutive proposals
// per iteration straight from registers. 4 proposals = 20 dwords = 5 aligned
// float4 loads (rpn) + 2 float4 loads (scores). No LDS, no barriers in the
// scan. Streamed once -> nontemporal hints to reduce L2 pollution.
__global__ __launch_bounds__(256) void trnms_kernel(
    const float* __restrict__ rois,      // (N,4)
    const float* __restrict__ rpn,       // (N,NPROP,5)
    const float* __restrict__ scores,    // (N,NPROP,2)
    float* __restrict__ out_rois,        // (N,4)
    float* __restrict__ out_scores)      // (N,1)
{
    const int i   = blockIdx.x;
    const int tid = threadIdx.x;

    // Reference ROI stats (identical expression order to numpy reference)
    const float rx1 = rois[i * 4 + 0], ry1 = rois[i * 4 + 1];
    const float rx2 = rois[i * 4 + 2], ry2 = rois[i * 4 + 3];
    const float x = (rx1 + rx2) * 0.5f;
    const float y = (ry1 + ry2) * 0.5f;
    const float w = fabsf(rx1 - rx2) + 0.0001f;
    const float h = fabsf(ry1 - ry2) + 0.0001f;
    const float p = (w + h) * 0.5f;
    const float s = sqrtf((w + p) * (h + p));
    const float ratio = w / h;
    const float r_max = fmaxf(ratio, 1.0f / ratio);
    const float window = s * 2.0f;

    const float* __restrict__ rowr  = rpn    + (long long)i * RPN_ROW;
    const float* __restrict__ rowsc = scores + (long long)i * SC_ROW;
    const f4* __restrict__ rowr4  = (const f4*)rowr;
    const f4* __restrict__ rowsc4 = (const f4*)rowsc;

    float best  = -INFINITY;
    int   besti = 0x7fffffff;

    // j strictly increases in processing order within a thread, so strict '>'
    // keeps the earliest index (numpy argmax tie-break).
    auto eval = [&](float px1, float py1, float px2, float py2, float scj, int j) {
        const float x_ = (px1 + px2) * 0.5f;
        const float y_ = (py1 + py2) * 0.5f;
        const float w_ = fabsf(px1 - px2) + 0.0001f;
        const float h_ = fabsf(py1 - py2) + 0.0001f;
        const float p_ = (w_ + h_) * 0.5f;
        const float s_ = sqrtf((w_ + p_) * (h_ + p_));
        const float smax = fmaxf(s / s_, s_ / s);
        const float pen  = expf(-PANELTY_K * (smax * r_max - 1.0f));
        const float dx = x - x_;
        const float dy = y - y_;
        const float dist = sqrtf(dx * dx + dy * dy);
        float han = 0.5f + 0.5f * cosf(dist * PI_F / window);
        han = (dist > window) ? 0.0f : han;
        const float val = scj * pen + han * HANN_W;
        if (val > best) { best = val; besti = j; }
    };

    #pragma unroll
    for (int c = 0; c < 2; ++c) {
        const int t4 = c * 256 + tid;   // group of 4 proposals
        const int j0 = t4 * 4;
        if (j0 < NPROP) {               // 2000 % 4 == 0: groups are all-or-nothing
            // 5 float4 = 20 dwords = proposals j0..j0+3 (fields b,x1,y1,x2,y2)
            const f4 v0 = __builtin_nontemporal_load(&rowr4[t4 * 5 + 0]);
            const f4 v1 = __builtin_nontemporal_load(&rowr4[t4 * 5 + 1]);
            const f4 v2 = __builtin_nontemporal_load(&rowr4[t4 * 5 + 2]);
            const f4 v3 = __builtin_nontemporal_load(&rowr4[t4 * 5 + 3]);
            const f4 v4 = __builtin_nontemporal_load(&rowr4[t4 * 5 + 4]);
            // 2 float4 = 8 dwords = scores for proposals j0..j0+3
            const f4 s0 = __builtin_nontemporal_load(&rowsc4[t4 * 2 + 0]);
            const f4 s1 = __builtin_nontemporal_load(&rowsc4[t4 * 2 + 1]);

            eval(v0.y, v0.z, v0.w, v1.x, s0.y, j0 + 0);
            eval(v1.z, v1.w, v2.x, v2.y, s0.w, j0 + 1);
            eval(v2.w, v3.x, v3.y, v3.z, s1.y, j0 + 2);
            eval(v4.x, v4.y, v4.z, v4.w, s1.w, j0 + 3);
        }
    }

    // ---- wave-level reduction (64 lanes), first-index tie-break ----
    #pragma unroll
    for (int off = 32; off > 0; off >>= 1) {
        const float ov = __shfl_down(best, off);
        const int   oi = __shfl_down(besti, off);
        if (ov > best || (ov == best && oi < besti)) { best = ov; besti = oi; }
    }

    __shared__ float sval[4];
    __shared__ int   sidx[4];
    const int wave = tid >> 6;
    if ((tid & 63) == 0) { sval[wave] = best; sidx[wave] = besti; }
    __syncthreads();

    if (tid == 0) {
        #pragma unroll
        for (int k = 1; k < 4; ++k) {
            const float ov = sval[k];
            const int   oi = sidx[k];
            if (ov > best || (ov == best && oi < besti)) { best = ov; besti = oi; }
        }
        out_rois[i * 4 + 0] = rowr[besti * 5 + 1];
        out_rois[i * 4 + 1] = rowr[besti * 5 + 2];
        out_rois[i * 4 + 2] = rowr[besti * 5 + 3];
        out_rois[i * 4 + 3] = rowr[besti * 5 + 4];
        out_scores[i] = rowsc[besti * 2 + 1];
    }
}

extern "C" void kernel_launch(void* const* d_in, const int* in_sizes, int n_in,
                              void* d_out, int out_size, void* d_ws, size_t ws_size,
                              hipStream_t stream) {
    const float* rois   = (const float*)d_in[0];  // (N,4)
    const float* rpn    = (const float*)d_in[1];  // (N,2000,5)
    const float* scores = (const float*)d_in[2];  // (N,2000,2)

    const int N = in_sizes[0] / 4;  // 8192

    float* out_rois   = (float*)d_out;          // first N*4 floats
    float* out_scores = (float*)d_out + N * 4;  // next N floats

    trnms_kernel<<<N, 256, 0, stream>>>(rois, rpn, scores, out_rois, out_scores);
}

// Round 4
// 503.282 us; speedup vs baseline: 1.0817x; 1.0817x over previous
//
#include <hip/hip_runtime.h>
#include <math.h>

#define NPROP 2000
#define RPN_ROW (NPROP * 5)       // 10000 floats per row
#define SC_ROW  (NPROP * 2)       // 4000 floats per row
#define PANELTY_K 0.055f
#define HANN_W 0.42f
#define PI_F 3.14159265358979323846f

typedef float f4 __attribute__((ext_vector_type(4)));

// One block per row; 256 threads; each thread computes 4 consecutive proposals
// per iteration straight from registers. 4 proposals = 20 dwords = 5 aligned
// float4 loads (rpn) + 2 float4 loads (scores). No LDS, no barriers in the
// scan. Regular (cached) loads: the harness's input-restore immediately before
// launch leaves much of the stream in L3 — nontemporal loads forfeited those
// hits and cost ~39 us in R3.
__global__ __launch_bounds__(256) void trnms_kernel(
    const float* __restrict__ rois,      // (N,4)
    const float* __restrict__ rpn,       // (N,NPROP,5)
    const float* __restrict__ scores,    // (N,NPROP,2)
    float* __restrict__ out_rois,        // (N,4)
    float* __restrict__ out_scores)      // (N,1)
{
    const int i   = blockIdx.x;
    const int tid = threadIdx.x;

    // Reference ROI stats (identical expression order to numpy reference)
    const float rx1 = rois[i * 4 + 0], ry1 = rois[i * 4 + 1];
    const float rx2 = rois[i * 4 + 2], ry2 = rois[i * 4 + 3];
    const float x = (rx1 + rx2) * 0.5f;
    const float y = (ry1 + ry2) * 0.5f;
    const float w = fabsf(rx1 - rx2) + 0.0001f;
    const float h = fabsf(ry1 - ry2) + 0.0001f;
    const float p = (w + h) * 0.5f;
    const float s = sqrtf((w + p) * (h + p));
    const float ratio = w / h;
    const float r_max = fmaxf(ratio, 1.0f / ratio);
    const float window = s * 2.0f;

    const float* __restrict__ rowr  = rpn    + (long long)i * RPN_ROW;
    const float* __restrict__ rowsc = scores + (long long)i * SC_ROW;
    const f4* __restrict__ rowr4  = (const f4*)rowr;
    const f4* __restrict__ rowsc4 = (const f4*)rowsc;

    float best  = -INFINITY;
    int   besti = 0x7fffffff;

    // j strictly increases in processing order within a thread, so strict '>'
    // keeps the earliest index (numpy argmax tie-break).
    auto eval = [&](float px1, float py1, float px2, float py2, float scj, int j) {
        const float x_ = (px1 + px2) * 0.5f;
        const float y_ = (py1 + py2) * 0.5f;
        const float w_ = fabsf(px1 - px2) + 0.0001f;
        const float h_ = fabsf(py1 - py2) + 0.0001f;
        const float p_ = (w_ + h_) * 0.5f;
        const float s_ = sqrtf((w_ + p_) * (h_ + p_));
        const float smax = fmaxf(s / s_, s_ / s);
        const float pen  = expf(-PANELTY_K * (smax * r_max - 1.0f));
        const float dx = x - x_;
        const float dy = y - y_;
        const float dist = sqrtf(dx * dx + dy * dy);
        float han = 0.5f + 0.5f * cosf(dist * PI_F / window);
        han = (dist > window) ? 0.0f : han;
        const float val = scj * pen + han * HANN_W;
        if (val > best) { best = val; besti = j; }
    };

    #pragma unroll
    for (int c = 0; c < 2; ++c) {
        const int t4 = c * 256 + tid;   // group of 4 proposals
        const int j0 = t4 * 4;
        if (j0 < NPROP) {               // 2000 % 4 == 0: groups are all-or-nothing
            // 5 float4 = 20 dwords = proposals j0..j0+3 (fields b,x1,y1,x2,y2)
            const f4 v0 = rowr4[t4 * 5 + 0];
            const f4 v1 = rowr4[t4 * 5 + 1];
            const f4 v2 = rowr4[t4 * 5 + 2];
            const f4 v3 = rowr4[t4 * 5 + 3];
            const f4 v4 = rowr4[t4 * 5 + 4];
            // 2 float4 = 8 dwords = scores for proposals j0..j0+3
            const f4 s0 = rowsc4[t4 * 2 + 0];
            const f4 s1 = rowsc4[t4 * 2 + 1];

            eval(v0.y, v0.z, v0.w, v1.x, s0.y, j0 + 0);
            eval(v1.z, v1.w, v2.x, v2.y, s0.w, j0 + 1);
            eval(v2.w, v3.x, v3.y, v3.z, s1.y, j0 + 2);
            eval(v4.x, v4.y, v4.z, v4.w, s1.w, j0 + 3);
        }
    }

    // ---- wave-level reduction (64 lanes), first-index tie-break ----
    #pragma unroll
    for (int off = 32; off > 0; off >>= 1) {
        const float ov = __shfl_down(best, off);
        const int   oi = __shfl_down(besti, off);
        if (ov > best || (ov == best && oi < besti)) { best = ov; besti = oi; }
    }

    __shared__ float sval[4];
    __shared__ int   sidx[4];
    const int wave = tid >> 6;
    if ((tid & 63) == 0) { sval[wave] = best; sidx[wave] = besti; }
    __syncthreads();

    if (tid == 0) {
        #pragma unroll
        for (int k = 1; k < 4; ++k) {
            const float ov = sval[k];
            const int   oi = sidx[k];
            if (ov > best || (ov == best && oi < besti)) { best = ov; besti = oi; }
        }
        out_rois[i * 4 + 0] = rowr[besti * 5 + 1];
        out_rois[i * 4 + 1] = rowr[besti * 5 + 2];
        out_rois[i * 4 + 2] = rowr[besti * 5 + 3];
        out_rois[i * 4 + 3] = rowr[besti * 5 + 4];
        out_scores[i] = rowsc[besti * 2 + 1];
    }
}

extern "C" void kernel_launch(void* const* d_in, const int* in_sizes, int n_in,
                              void* d_out, int out_size, void* d_ws, size_t ws_size,
                              hipStream_t stream) {
    const float* rois   = (const float*)d_in[0];  // (N,4)
    const float* rpn    = (const float*)d_in[1];  // (N,2000,5)
    const float* scores = (const float*)d_in[2];  // (N,2000,2)

    const int N = in_sizes[0] / 4;  // 8192

    float* out_rois   = (float*)d_out;          // first N*4 floats
    float* out_scores = (float*)d_out + N * 4;  // next N floats

    trnms_kernel<<<N, 256, 0, stream>>>(rois, rpn, scores, out_rois, out_scores);
}